// Round 8
// baseline (451.648 us; speedup 1.0000x reference)
//
#include <hip/hip_runtime.h>
#include <hip/hip_bf16.h>
#include <cstdint>
#include <cstddef>

#define H 256
#define EMB 16
#define ED 5
#define BN_EPS 1e-5f

typedef __attribute__((ext_vector_type(8))) short short8;
typedef __attribute__((ext_vector_type(4))) float f32x4;
typedef _Float16 h2 __attribute__((ext_vector_type(2)));

__device__ __forceinline__ unsigned short f2bf(float f) {
  unsigned int u = __float_as_uint(f);
  unsigned int r = (u + 0x7fffu + ((u >> 16) & 1u)) >> 16;
  return (unsigned short)r;
}
__device__ __forceinline__ unsigned int pk2bf(float a, float b) {
  return (unsigned int)f2bf(a) | ((unsigned int)f2bf(b) << 16);
}
__device__ __forceinline__ float bfhi(unsigned int u) {
  return __uint_as_float(u & 0xffff0000u);
}
__device__ __forceinline__ float bflo(unsigned int u) {
  return __uint_as_float(u << 16);
}
__device__ __forceinline__ h2 u2h2(unsigned int u) {
  union { unsigned int u; h2 h; } c;
  c.u = u;
  return c.h;
}
__device__ __forceinline__ unsigned int h22u(h2 h) {
  union { h2 h; unsigned int u; } c;
  c.h = h;
  return c.u;
}
__device__ __forceinline__ h2 mkh2(float a, float b) {
  h2 r;
  r.x = (_Float16)a;
  r.y = (_Float16)b;
  return r;
}

// -------------------------------------------------------------------------
// K1 (heterogeneous): blocks [0, CB) count degrees; blocks [CB, ...) do
// weight transposes + T table.  stats/deg zeroed by preceding memset.
// -------------------------------------------------------------------------
__global__ __launch_bounds__(256) void count_prep_kernel(
    const int* __restrict__ ei, int* __restrict__ deg,
    const float* __restrict__ Win, const float* __restrict__ W1,
    const float* __restrict__ W2, const float* __restrict__ gemb,
    const float* __restrict__ b_in, unsigned short* __restrict__ Wtx,
    unsigned short* __restrict__ Wt1, unsigned short* __restrict__ Wt2,
    float* __restrict__ T, int E, int F, int G, int CB) {
  if ((int)blockIdx.x < CB) {
    int e = blockIdx.x * 256 + threadIdx.x;
    if (e < E) atomicAdd(&deg[ei[E + e]], 1);
    return;
  }
  int idx = (blockIdx.x - CB) * 256 + threadIdx.x;
  if (idx < 256 * 128) {
    int n = idx >> 7, k = idx & 127;
    Wtx[idx] = f2bf((k < F) ? Win[(size_t)k * H + n] : 0.f);
  } else if (idx < 256 * 128 + 65536) {
    int i2 = idx - 256 * 128;
    int n = i2 >> 8, k = i2 & 255;
    Wt1[i2] = f2bf(W1[(size_t)k * H + n]);
  } else if (idx < 256 * 128 + 131072) {
    int i2 = idx - 256 * 128 - 65536;
    int n = i2 >> 8, k = i2 & 255;
    Wt2[i2] = f2bf(W2[(size_t)k * H + n]);
  } else if (idx < 256 * 128 + 131072 + G * 256) {
    int i2 = idx - 256 * 128 - 131072;
    int g = i2 >> 8, c = i2 & 255;
    float s = b_in[c];
    #pragma unroll
    for (int k = 0; k < EMB; ++k)
      s = fmaf(gemb[g * EMB + k], Win[(size_t)(F + k) * H + c], s);
    T[i2] = s;
  }
}

// -------------------------------------------------------------------------
// Scan: per-block exclusive scan + block sums, then finish adds prefix.
// -------------------------------------------------------------------------
__global__ __launch_bounds__(256) void scan_blocks_kernel(
    const int* __restrict__ deg, int* __restrict__ excl,
    int* __restrict__ bsums, int n) {
  const int tid = threadIdx.x;
  const int i = blockIdx.x * 256 + tid;
  const int lane = tid & 63, wid = tid >> 6;
  int v = (i < n) ? deg[i] : 0;
  int x = v;
  #pragma unroll
  for (int d = 1; d < 64; d <<= 1) {
    int y = __shfl_up(x, d, 64);
    if (lane >= d) x += y;
  }
  __shared__ int ws[4], wo[4];
  if (lane == 63) ws[wid] = x;
  __syncthreads();
  if (tid == 0) {
    int a = 0;
    #pragma unroll
    for (int w = 0; w < 4; ++w) { wo[w] = a; a += ws[w]; }
    bsums[blockIdx.x] = a;
  }
  __syncthreads();
  if (i < n) excl[i] = x - v + wo[wid];
}

__global__ __launch_bounds__(256) void scan_finish_kernel(
    int* __restrict__ row_start, int* __restrict__ cursor,
    const int* __restrict__ bsums, int n, int E, int NB) {
  const int tid = threadIdx.x;
  const int b = blockIdx.x;
  int v = (tid < b && tid < NB) ? bsums[tid] : 0;
  int s = v;
  #pragma unroll
  for (int d = 32; d > 0; d >>= 1) s += __shfl_down(s, d, 64);
  __shared__ int ws[4];
  if ((tid & 63) == 0) ws[tid >> 6] = s;
  __syncthreads();
  const int S = ws[0] + ws[1] + ws[2] + ws[3];
  const int i = b * 256 + tid;
  if (i < n) {
    int r = row_start[i] + S;
    row_start[i] = r;
    cursor[i] = r;
  }
  if (b == 0 && tid == 0) row_start[n] = E;
}

// -------------------------------------------------------------------------
// K4 (heterogeneous): blocks [0, SB) scatter CSR records {src, ea[5]fp16}
// + fp32 ea passthrough; blocks [SB, SB+GB) run the fused input GEMM
// (h0 = relu(x@Wx + T[gid]) bf16 + BN column stats).
// -------------------------------------------------------------------------
__global__ __launch_bounds__(256) void scatter_gemm_kernel(
    const int* __restrict__ ei, const float* __restrict__ ea,
    int* __restrict__ cursor, uint4* __restrict__ rec,
    float* __restrict__ ea_out,
    const float* __restrict__ x, const int* __restrict__ gid,
    const unsigned short* __restrict__ Wtx, const float* __restrict__ T,
    unsigned short* __restrict__ h0, float* __restrict__ stats,
    int E, int F, int SB) {
  __shared__ __align__(16) unsigned short As[128][40];
  __shared__ __align__(16) unsigned short Bs[128][40];
  __shared__ float cs[128], css[128];
  if ((int)blockIdx.x < SB) {
    int e = blockIdx.x * 256 + threadIdx.x;
    if (e >= E) return;
    int s = ei[e];
    int d = ei[E + e];
    int p = atomicAdd(&cursor[d], 1);
    const float* eap = ea + (size_t)e * ED;
    const float e0 = eap[0], e1 = eap[1], e2 = eap[2], e3 = eap[3], e4 = eap[4];
    uint4 r;
    r.x = (unsigned)s;
    r.y = h22u(mkh2(e0, e1));
    r.z = h22u(mkh2(e2, e3));
    r.w = h22u(mkh2(e4, 0.f));
    rec[p] = r;
    float* op = ea_out + (size_t)e * ED;
    op[0] = e0; op[1] = e1; op[2] = e2; op[3] = e3; op[4] = e4;
    return;
  }
  // ---- input GEMM part ----
  const int bx = blockIdx.x - SB;
  const int m0 = (bx >> 1) * 128;
  const int n0 = (bx & 1) * 128;
  const int tid = threadIdx.x;
  const int lane = tid & 63;
  const int wave = tid >> 6;
  const int wm = (wave & 1) * 64;
  const int wn = (wave >> 1) * 64;
  const int l16 = lane & 15;
  const int quad = lane >> 4;
  if (tid < 128) {
    cs[tid] = 0.f;
    css[tid] = 0.f;
  }
  f32x4 acc[4][4] = {};
  const int srow = tid >> 1;
  const int half = tid & 1;
  for (int k0 = 0; k0 < 128; k0 += 32) {
    __syncthreads();
    {
      const float* xp = x + (size_t)(m0 + srow) * F;
      float4 xv[4];
      #pragma unroll
      for (int f = 0; f < 4; ++f) {
        int c = k0 + half * 16 + f * 4;
        xv[f] = (c < F) ? *(const float4*)(xp + c)
                        : make_float4(0.f, 0.f, 0.f, 0.f);
      }
      uint4 p0, p1;
      p0.x = pk2bf(xv[0].x, xv[0].y); p0.y = pk2bf(xv[0].z, xv[0].w);
      p0.z = pk2bf(xv[1].x, xv[1].y); p0.w = pk2bf(xv[1].z, xv[1].w);
      p1.x = pk2bf(xv[2].x, xv[2].y); p1.y = pk2bf(xv[2].z, xv[2].w);
      p1.z = pk2bf(xv[3].x, xv[3].y); p1.w = pk2bf(xv[3].z, xv[3].w);
      *(uint4*)(&As[srow][half * 16]) = p0;
      *(uint4*)(&As[srow][half * 16 + 8]) = p1;
    }
    {
      const unsigned short* wp = Wtx + (size_t)(n0 + srow) * 128 + k0 + half * 16;
      *(uint4*)(&Bs[srow][half * 16]) = *(const uint4*)wp;
      *(uint4*)(&Bs[srow][half * 16 + 8]) = *(const uint4*)(wp + 8);
    }
    __syncthreads();
    short8 af[4], bf[4];
    #pragma unroll
    for (int i = 0; i < 4; ++i)
      af[i] = *(const short8*)(&As[wm + i * 16 + l16][quad * 8]);
    #pragma unroll
    for (int j = 0; j < 4; ++j)
      bf[j] = *(const short8*)(&Bs[wn + j * 16 + l16][quad * 8]);
    #pragma unroll
    for (int i = 0; i < 4; ++i)
      #pragma unroll
      for (int j = 0; j < 4; ++j)
        acc[i][j] = __builtin_amdgcn_mfma_f32_16x16x32_bf16(af[i], bf[j],
                                                            acc[i][j], 0, 0, 0);
  }
  int gi[4][4];
  #pragma unroll
  for (int i = 0; i < 4; ++i)
    #pragma unroll
    for (int r = 0; r < 4; ++r)
      gi[i][r] = gid[m0 + wm + i * 16 + quad * 4 + r];
  float ls[4] = {}, lss[4] = {};
  #pragma unroll
  for (int j = 0; j < 4; ++j) {
    const int col = n0 + wn + j * 16 + l16;
    #pragma unroll
    for (int i = 0; i < 4; ++i) {
      #pragma unroll
      for (int r = 0; r < 4; ++r) {
        const int row = m0 + wm + i * 16 + quad * 4 + r;
        float v = fmaxf(acc[i][j][r] + T[gi[i][r] * H + col], 0.f);
        h0[(size_t)row * H + col] = f2bf(v);
        ls[j] += v;
        lss[j] = fmaf(v, v, lss[j]);
      }
    }
  }
  #pragma unroll
  for (int j = 0; j < 4; ++j) {
    const int lc = wn + j * 16 + l16;
    atomicAdd(&cs[lc], ls[j]);
    atomicAdd(&css[lc], lss[j]);
  }
  __syncthreads();
  if (tid < 128) {
    atomicAdd(&stats[n0 + tid], cs[tid]);
    atomicAdd(&stats[H + n0 + tid], css[tid]);
  }
}

// -------------------------------------------------------------------------
// hbn(fp16) = a*h0 + b + be  (BN finalize + GINE edge-bias folded in)
// -------------------------------------------------------------------------
__global__ __launch_bounds__(256) void hbn_kernel(
    const unsigned short* __restrict__ h0, const float* __restrict__ stats,
    const float* __restrict__ gamma, const float* __restrict__ beta,
    const float* __restrict__ be, unsigned short* __restrict__ hbn,
    float inv_n) {
  __shared__ float sa[H], sb[H];
  {
    const int j = threadIdx.x;
    const float mu = stats[j] * inv_n;
    const float var = stats[H + j] * inv_n - mu * mu;
    const float rs = 1.0f / sqrtf(var + BN_EPS);
    const float a = gamma[j] * rs;
    sa[j] = a;
    sb[j] = beta[j] - mu * a + be[j];
  }
  __syncthreads();
  const size_t i = (size_t)blockIdx.x * 256 + threadIdx.x;
  const int c = ((int)(i & 31)) * 8;
  const uint4 hv = ((const uint4*)h0)[i];
  float r[8] = {bflo(hv.x), bfhi(hv.x), bflo(hv.y), bfhi(hv.y),
                bflo(hv.z), bfhi(hv.z), bflo(hv.w), bfhi(hv.w)};
  float o[8];
  #pragma unroll
  for (int t = 0; t < 8; ++t)
    o[t] = fmaf(sa[c + t], r[t], sb[c + t]);
  uint4 ov;
  ov.x = h22u(mkh2(o[0], o[1]));
  ov.y = h22u(mkh2(o[2], o[3]));
  ov.z = h22u(mkh2(o[4], o[5]));
  ov.w = h22u(mkh2(o[6], o[7]));
  ((uint4*)hbn)[i] = ov;
}

// -------------------------------------------------------------------------
// K6: fused aggregate + 2-layer MLP.  Block = 64 nodes.
// Phase A: wave w gathers/aggregates nodes w*16..w*16+15 -> zS (bf16, LDS)
// Phase B: hid = relu(zS@W1+b1) (acc regs) -> overwrite zS
// Phase C: out = relu(zS@W2+b2) -> global fp32
// -------------------------------------------------------------------------
__device__ __forceinline__ void edge_accum(
    const uint4 rr, const uint2 hv, const h2 wA[5], const h2 wB[5],
    float& ax, float& ay, float& az, float& aw) {
  h2 m01 = u2h2(hv.x);
  h2 m23 = u2h2(hv.y);
  const h2 e01 = u2h2(rr.y), e23 = u2h2(rr.z), e44 = u2h2(rr.w);
  h2 t;
  t.x = e01.x; t.y = e01.x;  m01 += t * wA[0]; m23 += t * wB[0];
  t.x = e01.y; t.y = e01.y;  m01 += t * wA[1]; m23 += t * wB[1];
  t.x = e23.x; t.y = e23.x;  m01 += t * wA[2]; m23 += t * wB[2];
  t.x = e23.y; t.y = e23.y;  m01 += t * wA[3]; m23 += t * wB[3];
  t.x = e44.x; t.y = e44.x;  m01 += t * wA[4]; m23 += t * wB[4];
  const h2 z2 = {(_Float16)0.f, (_Float16)0.f};
  m01 = __builtin_elementwise_max(m01, z2);
  m23 = __builtin_elementwise_max(m23, z2);
  ax += (float)m01.x;
  ay += (float)m01.y;
  az += (float)m23.x;
  aw += (float)m23.y;
}

__global__ __launch_bounds__(256) void agg_mlp_kernel(
    const unsigned short* __restrict__ hbn, const uint4* __restrict__ rec,
    const float* __restrict__ We, const float* __restrict__ be,
    const int* __restrict__ row_start,
    const unsigned short* __restrict__ Wt1,
    const unsigned short* __restrict__ Wt2, const float* __restrict__ b1,
    const float* __restrict__ b2, float* __restrict__ out, int N) {
  const int tid = threadIdx.x;
  const int lane = tid & 63;
  const int wave = tid >> 6;
  const int m0 = blockIdx.x * 64;
  __shared__ __align__(16) unsigned short zS[64][264];
  __shared__ __align__(16) unsigned short Bs[256][40];
  // ---- Phase A: aggregate 16 nodes per wave ----
  {
    const int c = lane * 4;
    const float4 be4 = *(const float4*)(be + c);
    h2 wA[5], wB[5];
    #pragma unroll
    for (int k = 0; k < 5; ++k) {
      wA[k] = mkh2(We[k * H + c], We[k * H + c + 1]);
      wB[k] = mkh2(We[k * H + c + 2], We[k * H + c + 3]);
    }
    for (int t = 0; t < 16; ++t) {
      const int n = __builtin_amdgcn_readfirstlane(m0 + wave * 16 + t);
      const int s0 = __builtin_amdgcn_readfirstlane(row_start[n]);
      const int s1 = __builtin_amdgcn_readfirstlane(row_start[n + 1]);
      const uint4* rp = rec + s0;
      const int cnt = s1 - s0;
      float ax = 0.f, ay = 0.f, az = 0.f, aw = 0.f;
      int i = 0;
      for (; i + 4 <= cnt; i += 4) {
        uint4 rr[4];
        uint2 hh[4];
        #pragma unroll
        for (int u = 0; u < 4; ++u) rr[u] = rp[i + u];
        #pragma unroll
        for (int u = 0; u < 4; ++u)
          hh[u] = *(const uint2*)(hbn + (size_t)(int)rr[u].x * H + c);
        #pragma unroll
        for (int u = 0; u < 4; ++u)
          edge_accum(rr[u], hh[u], wA, wB, ax, ay, az, aw);
      }
      for (; i < cnt; ++i) {
        const uint4 r0 = rp[i];
        const uint2 h0v = *(const uint2*)(hbn + (size_t)(int)r0.x * H + c);
        edge_accum(r0, h0v, wA, wB, ax, ay, az, aw);
      }
      const uint2 hs = *(const uint2*)(hbn + (size_t)n * H + c);
      const h2 hsA = u2h2(hs.x), hsB = u2h2(hs.y);
      uint2 o;
      o.x = pk2bf((float)hsA.x - be4.x + ax, (float)hsA.y - be4.y + ay);
      o.y = pk2bf((float)hsB.x - be4.z + az, (float)hsB.y - be4.w + aw);
      *(uint2*)(&zS[wave * 16 + t][c]) = o;
    }
  }
  __syncthreads();
  // ---- Phase B: layer 1 ----
  const int l16 = lane & 15;
  const int quad = lane >> 4;
  const int wn = wave * 64;
  const int ar = tid >> 2, ac = tid & 3;
  f32x4 acc[4][4] = {};
  for (int k0 = 0; k0 < 256; k0 += 32) {
    __syncthreads();
    #pragma unroll
    for (int t = 0; t < 4; ++t) {
      int r = ar + t * 64;
      *(float4*)(&Bs[r][ac * 8]) =
          *(const float4*)(Wt1 + (size_t)r * H + k0 + ac * 8);
    }
    __syncthreads();
    short8 af[4], bf[4];
    #pragma unroll
    for (int i = 0; i < 4; ++i)
      af[i] = *(const short8*)(&zS[i * 16 + l16][k0 + quad * 8]);
    #pragma unroll
    for (int j = 0; j < 4; ++j)
      bf[j] = *(const short8*)(&Bs[wn + j * 16 + l16][quad * 8]);
    #pragma unroll
    for (int i = 0; i < 4; ++i)
      #pragma unroll
      for (int j = 0; j < 4; ++j)
        acc[i][j] = __builtin_amdgcn_mfma_f32_16x16x32_bf16(af[i], bf[j],
                                                            acc[i][j], 0, 0, 0);
  }
  __syncthreads();  // all zS reads done; safe to overwrite
  #pragma unroll
  for (int j = 0; j < 4; ++j) {
    const int col = wn + j * 16 + l16;
    const float bj = b1[col];
    #pragma unroll
    for (int i = 0; i < 4; ++i)
      #pragma unroll
      for (int r = 0; r < 4; ++r) {
        const int row = i * 16 + quad * 4 + r;
        zS[row][col] = f2bf(fmaxf(acc[i][j][r] + bj, 0.f));
      }
  }
  #pragma unroll
  for (int i = 0; i < 4; ++i)
    #pragma unroll
    for (int j = 0; j < 4; ++j)
      acc[i][j] = (f32x4){0.f, 0.f, 0.f, 0.f};
  __syncthreads();
  // ---- Phase C: layer 2 ----
  for (int k0 = 0; k0 < 256; k0 += 32) {
    __syncthreads();
    #pragma unroll
    for (int t = 0; t < 4; ++t) {
      int r = ar + t * 64;
      *(float4*)(&Bs[r][ac * 8]) =
          *(const float4*)(Wt2 + (size_t)r * H + k0 + ac * 8);
    }
    __syncthreads();
    short8 af[4], bf[4];
    #pragma unroll
    for (int i = 0; i < 4; ++i)
      af[i] = *(const short8*)(&zS[i * 16 + l16][k0 + quad * 8]);
    #pragma unroll
    for (int j = 0; j < 4; ++j)
      bf[j] = *(const short8*)(&Bs[wn + j * 16 + l16][quad * 8]);
    #pragma unroll
    for (int i = 0; i < 4; ++i)
      #pragma unroll
      for (int j = 0; j < 4; ++j)
        acc[i][j] = __builtin_amdgcn_mfma_f32_16x16x32_bf16(af[i], bf[j],
                                                            acc[i][j], 0, 0, 0);
  }
  #pragma unroll
  for (int j = 0; j < 4; ++j) {
    const int col = wn + j * 16 + l16;
    const float bj = b2[col];
    #pragma unroll
    for (int i = 0; i < 4; ++i)
      #pragma unroll
      for (int r = 0; r < 4; ++r) {
        const int row = m0 + i * 16 + quad * 4 + r;
        out[(size_t)row * H + col] = fmaxf(acc[i][j][r] + bj, 0.f);
      }
  }
}

// -------------------------------------------------------------------------
extern "C" void kernel_launch(void* const* d_in, const int* in_sizes, int n_in,
                              void* d_out, int out_size, void* d_ws, size_t ws_size,
                              hipStream_t stream) {
  const float* x     = (const float*)d_in[0];
  const int*   ei    = (const int*)d_in[1];
  const float* ea    = (const float*)d_in[2];
  const int*   gid   = (const int*)d_in[3];
  const float* gemb  = (const float*)d_in[4];
  const float* W_in  = (const float*)d_in[5];
  const float* b_in  = (const float*)d_in[6];
  const float* gamma = (const float*)d_in[7];
  const float* beta  = (const float*)d_in[8];
  const float* We    = (const float*)d_in[9];
  const float* be    = (const float*)d_in[10];
  const float* W1    = (const float*)d_in[11];
  const float* b1    = (const float*)d_in[12];
  const float* W2    = (const float*)d_in[13];
  const float* b2    = (const float*)d_in[14];
  float* out = (float*)d_out;

  const int N = in_sizes[3];           // 59392
  const int E = in_sizes[1] / 2;       // 950272
  const int F = in_sizes[0] / N;       // 116
  const int G = in_sizes[4] / EMB;     // 8
  const int NB = (N + 255) / 256;      // 232
  const int CB = (E + 255) / 256;      // 3712 count/scatter blocks

  char* p = (char*)d_ws;
  auto take = [&](size_t bytes) {
    char* r = p;
    p += (bytes + 255) & ~(size_t)255;
    return r;
  };
  float* stats          = (float*)take(4096);
  int* deg              = (int*)take((size_t)N * 4);
  int* row_start        = (int*)take((size_t)(N + 1) * 4);
  int* cursor           = (int*)take((size_t)N * 4);
  int* bsums            = (int*)take((size_t)NB * 4);
  uint4* rec            = (uint4*)take((size_t)E * 16);
  unsigned short* Wtx   = (unsigned short*)take((size_t)256 * 128 * 2);
  unsigned short* Wt1   = (unsigned short*)take((size_t)H * H * 2);
  unsigned short* Wt2   = (unsigned short*)take((size_t)H * H * 2);
  float* T              = (float*)take((size_t)G * H * 4);
  unsigned short* h0    = (unsigned short*)take((size_t)N * H * 2);
  unsigned short* hbn   = (unsigned short*)take((size_t)N * H * 2);

  // 0) zero stats (4096B pad) + deg
  (void)hipMemsetAsync(stats, 0, 4096 + (size_t)N * 4, stream);

  // 1) count + prep (heterogeneous)
  {
    int prep_total = 256 * 128 + 131072 + G * 256;
    int nb = CB + (prep_total + 255) / 256;
    count_prep_kernel<<<nb, 256, 0, stream>>>(ei, deg, W_in, W1, W2, gemb,
                                              b_in, Wtx, Wt1, Wt2, T, E, F, G,
                                              CB);
  }

  // 2-3) scan
  scan_blocks_kernel<<<NB, 256, 0, stream>>>(deg, row_start, bsums, N);
  scan_finish_kernel<<<NB, 256, 0, stream>>>(row_start, cursor, bsums, N, E, NB);

  // 4) scatter + input GEMM (heterogeneous)
  scatter_gemm_kernel<<<CB + (N / 128) * 2, 256, 0, stream>>>(
      ei, ea, cursor, rec, out + (size_t)N * H, x, gid, Wtx, T, h0, stats, E,
      F, CB);

  // 5) BN finalize + be fold -> fp16 hbn
  hbn_kernel<<<((size_t)N * H / 8) / 256, 256, 0, stream>>>(
      h0, stats, gamma, beta, be, hbn, 1.0f / (float)N);

  // 6) fused aggregate + MLP -> out
  agg_mlp_kernel<<<N / 64, 256, 0, stream>>>(hbn, rec, We, be, row_start, Wt1,
                                             Wt2, b1, b2, out, N);
}